// Round 1
// baseline (7471.008 us; speedup 1.0000x reference)
//
#include <hip/hip_runtime.h>
#include <math.h>

#define NHEADS 8
#define NC 9
#define NHC 72
#define FIN 12

__device__ __forceinline__ unsigned f2o(float f) {
    unsigned u = __float_as_uint(f);
    return (u & 0x80000000u) ? ~u : (u | 0x80000000u);
}
__device__ __forceinline__ float o2f(unsigned u) {
    return (u & 0x80000000u) ? __uint_as_float(u ^ 0x80000000u) : __uint_as_float(~u);
}
__device__ __forceinline__ float lrelu(float v) { return v > 0.f ? v : 0.2f * v; }

// K1: per-node linear transform, attention halves, and accumulator init.
__global__ void __launch_bounds__(256) k_transform(
    const float* __restrict__ x, const float* __restrict__ W,
    const float* __restrict__ a_src, const float* __restrict__ a_dst,
    float* __restrict__ hbuf, float* __restrict__ al_s, float* __restrict__ al_d,
    unsigned* __restrict__ m_enc, float* __restrict__ denom,
    float* __restrict__ out_acc, int N)
{
    __shared__ float sW[FIN * NHC];
    __shared__ float sas[NHC];
    __shared__ float sad[NHC];
    int tid = threadIdx.x;
    for (int i = tid; i < FIN * NHC; i += blockDim.x) sW[i] = W[i];
    if (tid < NHC) { sas[tid] = a_src[tid]; sad[tid] = a_dst[tid]; }
    __syncthreads();
    int n = blockIdx.x * blockDim.x + tid;
    if (n >= N) return;

    float xv[FIN];
    const float4* xp = reinterpret_cast<const float4*>(x + (size_t)n * FIN);
    float4 q0 = xp[0], q1 = xp[1], q2 = xp[2];
    xv[0] = q0.x; xv[1] = q0.y; xv[2] = q0.z; xv[3] = q0.w;
    xv[4] = q1.x; xv[5] = q1.y; xv[6] = q1.z; xv[7] = q1.w;
    xv[8] = q2.x; xv[9] = q2.y; xv[10] = q2.z; xv[11] = q2.w;

    float acc[NHC];
    #pragma unroll
    for (int j = 0; j < NHC; ++j) acc[j] = 0.f;
    #pragma unroll
    for (int k = 0; k < FIN; ++k) {
        float xk = xv[k];
        #pragma unroll
        for (int j = 0; j < NHC; ++j) acc[j] = fmaf(xk, sW[k * NHC + j], acc[j]);
    }

    float* hp = hbuf + (size_t)n * NHC;
    float* oa = out_acc + (size_t)n * NHC;
    #pragma unroll
    for (int j = 0; j < NHC; ++j) { hp[j] = acc[j]; oa[j] = 0.f; }

    #pragma unroll
    for (int hh = 0; hh < NHEADS; ++hh) {
        float ss = 0.f, dd = 0.f;
        #pragma unroll
        for (int c = 0; c < NC; ++c) {
            ss = fmaf(acc[hh * NC + c], sas[hh * NC + c], ss);
            dd = fmaf(acc[hh * NC + c], sad[hh * NC + c], dd);
        }
        al_s[(size_t)n * NHEADS + hh] = ss;
        al_d[(size_t)n * NHEADS + hh] = dd;
        m_enc[(size_t)n * NHEADS + hh] = 0u;   // < encode(-inf), so any real logit wins
        denom[(size_t)n * NHEADS + hh] = 0.f;
    }
}

// K2: edge-wise segment max (atomicMax on order-preserving uint encoding).
__global__ void __launch_bounds__(256) k_max(
    const int* __restrict__ src, const int* __restrict__ dst,
    const float* __restrict__ al_s, const float* __restrict__ al_d,
    unsigned* __restrict__ m_enc, int E, int N)
{
    int i = blockIdx.x * blockDim.x + threadIdx.x;
    if (i >= E + N) return;
    int s, d;
    if (i < E) { s = src[i]; d = dst[i]; } else { s = i - E; d = s; }
    const float* as = al_s + (size_t)s * NHEADS;
    const float* ad = al_d + (size_t)d * NHEADS;
    unsigned* mp = m_enc + (size_t)d * NHEADS;
    #pragma unroll
    for (int hh = 0; hh < NHEADS; ++hh) {
        float logit = lrelu(as[hh] + ad[hh]);
        atomicMax(mp + hh, f2o(logit));
    }
}

// K3: edge-wise exp + scatter-accumulate (unnormalized) + denom.
__global__ void __launch_bounds__(256) k_agg(
    const int* __restrict__ src, const int* __restrict__ dst,
    const float* __restrict__ al_s, const float* __restrict__ al_d,
    const unsigned* __restrict__ m_enc, const float* __restrict__ hbuf,
    float* __restrict__ denom, float* __restrict__ out_acc, int E, int N)
{
    int i = blockIdx.x * blockDim.x + threadIdx.x;
    if (i >= E + N) return;
    int s, d;
    if (i < E) { s = src[i]; d = dst[i]; } else { s = i - E; d = s; }
    const float* as = al_s + (size_t)s * NHEADS;
    const float* ad = al_d + (size_t)d * NHEADS;
    const unsigned* mp = m_enc + (size_t)d * NHEADS;
    float ex[NHEADS];
    #pragma unroll
    for (int hh = 0; hh < NHEADS; ++hh) {
        float logit = lrelu(as[hh] + ad[hh]);
        ex[hh] = expf(logit - o2f(mp[hh]));
        atomicAdd(denom + (size_t)d * NHEADS + hh, ex[hh]);
    }
    const float* hs = hbuf + (size_t)s * NHC;
    float* oa = out_acc + (size_t)d * NHC;
    #pragma unroll
    for (int hh = 0; hh < NHEADS; ++hh) {
        #pragma unroll
        for (int c = 0; c < NC; ++c) {
            atomicAdd(oa + hh * NC + c, ex[hh] * hs[hh * NC + c]);
        }
    }
}

// K4: normalize, head-mean, bias, log-softmax.
__global__ void __launch_bounds__(256) k_final(
    const float* __restrict__ out_acc, const float* __restrict__ denom,
    const float* __restrict__ bias, float* __restrict__ out, int N)
{
    int n = blockIdx.x * blockDim.x + threadIdx.x;
    if (n >= N) return;
    float v[NC];
    #pragma unroll
    for (int c = 0; c < NC; ++c) v[c] = 0.f;
    const float* oa = out_acc + (size_t)n * NHC;
    const float* dn = denom + (size_t)n * NHEADS;
    #pragma unroll
    for (int hh = 0; hh < NHEADS; ++hh) {
        float inv = 1.f / (dn[hh] + 1e-16f);
        #pragma unroll
        for (int c = 0; c < NC; ++c) v[c] = fmaf(oa[hh * NC + c], inv, v[c]);
    }
    #pragma unroll
    for (int c = 0; c < NC; ++c) v[c] = v[c] * 0.125f + bias[c];
    float mx = v[0];
    #pragma unroll
    for (int c = 1; c < NC; ++c) mx = fmaxf(mx, v[c]);
    float sum = 0.f;
    #pragma unroll
    for (int c = 0; c < NC; ++c) sum += expf(v[c] - mx);
    float lse = mx + logf(sum);
    float* op = out + (size_t)n * NC;
    #pragma unroll
    for (int c = 0; c < NC; ++c) op[c] = v[c] - lse;
}

extern "C" void kernel_launch(void* const* d_in, const int* in_sizes, int n_in,
                              void* d_out, int out_size, void* d_ws, size_t ws_size,
                              hipStream_t stream)
{
    const float* x     = (const float*)d_in[0];
    const int*   ei    = (const int*)d_in[1];
    const float* W     = (const float*)d_in[2];
    const float* a_src = (const float*)d_in[3];
    const float* a_dst = (const float*)d_in[4];
    const float* bias  = (const float*)d_in[5];

    int N = in_sizes[0] / FIN;   // 100000
    int E = in_sizes[1] / 2;     // 1600000
    const int* src = ei;
    const int* dst = ei + E;

    char* ws = (char*)d_ws;
    float*    hbuf    = (float*)ws;    ws += (size_t)N * NHC * sizeof(float);
    float*    al_s    = (float*)ws;    ws += (size_t)N * NHEADS * sizeof(float);
    float*    al_d    = (float*)ws;    ws += (size_t)N * NHEADS * sizeof(float);
    unsigned* m_enc   = (unsigned*)ws; ws += (size_t)N * NHEADS * sizeof(unsigned);
    float*    denom   = (float*)ws;    ws += (size_t)N * NHEADS * sizeof(float);
    float*    out_acc = (float*)ws;    ws += (size_t)N * NHC * sizeof(float);

    int nb_n = (N + 255) / 256;
    int nb_e = (E + N + 255) / 256;
    k_transform<<<nb_n, 256, 0, stream>>>(x, W, a_src, a_dst, hbuf, al_s, al_d,
                                          m_enc, denom, out_acc, N);
    k_max<<<nb_e, 256, 0, stream>>>(src, dst, al_s, al_d, m_enc, E, N);
    k_agg<<<nb_e, 256, 0, stream>>>(src, dst, al_s, al_d, m_enc, hbuf, denom,
                                    out_acc, E, N);
    k_final<<<nb_n, 256, 0, stream>>>(out_acc, denom, bias, (float*)d_out, N);
}

// Round 2
// 676.338 us; speedup vs baseline: 11.0463x; 11.0463x over previous
//
#include <hip/hip_runtime.h>
#include <math.h>

#define NHEADS 8
#define NC 9
#define NHC 72
#define FIN 12
#define WAVES_PER_BLOCK 4
#define SCAN_T 1024

__device__ __forceinline__ float lrelu(float v) { return v > 0.f ? v : 0.2f * v; }

__device__ __forceinline__ void load8(float* v, const float* p) {
    const float4* q = reinterpret_cast<const float4*>(p);
    float4 a = q[0], b = q[1];
    v[0]=a.x; v[1]=a.y; v[2]=a.z; v[3]=a.w;
    v[4]=b.x; v[5]=b.y; v[6]=b.z; v[7]=b.w;
}

// K1: per-node linear transform + attention halves.
__global__ void __launch_bounds__(256) k_transform(
    const float* __restrict__ x, const float* __restrict__ W,
    const float* __restrict__ a_src, const float* __restrict__ a_dst,
    float* __restrict__ hbuf, float* __restrict__ al_s, float* __restrict__ al_d,
    int N)
{
    __shared__ float sW[FIN * NHC];
    __shared__ float sas[NHC];
    __shared__ float sad[NHC];
    int tid = threadIdx.x;
    for (int i = tid; i < FIN * NHC; i += blockDim.x) sW[i] = W[i];
    if (tid < NHC) { sas[tid] = a_src[tid]; sad[tid] = a_dst[tid]; }
    __syncthreads();
    int n = blockIdx.x * blockDim.x + tid;
    if (n >= N) return;

    float xv[FIN];
    const float4* xp = reinterpret_cast<const float4*>(x + (size_t)n * FIN);
    float4 q0 = xp[0], q1 = xp[1], q2 = xp[2];
    xv[0] = q0.x; xv[1] = q0.y; xv[2] = q0.z; xv[3] = q0.w;
    xv[4] = q1.x; xv[5] = q1.y; xv[6] = q1.z; xv[7] = q1.w;
    xv[8] = q2.x; xv[9] = q2.y; xv[10] = q2.z; xv[11] = q2.w;

    float acc[NHC];
    #pragma unroll
    for (int j = 0; j < NHC; ++j) acc[j] = 0.f;
    #pragma unroll
    for (int k = 0; k < FIN; ++k) {
        float xk = xv[k];
        #pragma unroll
        for (int j = 0; j < NHC; ++j) acc[j] = fmaf(xk, sW[k * NHC + j], acc[j]);
    }

    float* hp = hbuf + (size_t)n * NHC;
    #pragma unroll
    for (int j = 0; j < NHC; ++j) hp[j] = acc[j];

    #pragma unroll
    for (int hh = 0; hh < NHEADS; ++hh) {
        float ss = 0.f, dd = 0.f;
        #pragma unroll
        for (int c = 0; c < NC; ++c) {
            ss = fmaf(acc[hh * NC + c], sas[hh * NC + c], ss);
            dd = fmaf(acc[hh * NC + c], sad[hh * NC + c], dd);
        }
        al_s[(size_t)n * NHEADS + hh] = ss;
        al_d[(size_t)n * NHEADS + hh] = dd;
    }
}

// K2: in-degree count (real edges only; self-loops implicit).
__global__ void __launch_bounds__(256) k_degree(
    const int* __restrict__ dst, int* __restrict__ deg, int E)
{
    int i = blockIdx.x * blockDim.x + threadIdx.x;
    if (i < E) atomicAdd(&deg[dst[i]], 1);
}

// K3: single-block exclusive scan of deg -> rowptr, cursor.
__global__ void __launch_bounds__(SCAN_T) k_scan(
    const int* __restrict__ deg, int* __restrict__ rowptr,
    int* __restrict__ cursor, int N)
{
    __shared__ int sums[SCAN_T];
    int t = threadIdx.x;
    int chunk = (N + SCAN_T - 1) / SCAN_T;
    int start = t * chunk;
    int end = min(N, start + chunk);
    int s = 0;
    for (int i = start; i < end; ++i) s += deg[i];
    sums[t] = s;
    __syncthreads();
    for (int off = 1; off < SCAN_T; off <<= 1) {
        int v = (t >= off) ? sums[t - off] : 0;
        __syncthreads();
        sums[t] += v;
        __syncthreads();
    }
    int run = (t == 0) ? 0 : sums[t - 1];
    for (int i = start; i < end; ++i) {
        int dv = deg[i];
        rowptr[i] = run;
        cursor[i] = run;
        run += dv;
    }
    if (start < N && end == N) rowptr[N] = run;
}

// K4: scatter edge src indices into CSR slots.
__global__ void __launch_bounds__(256) k_scatter(
    const int* __restrict__ src, const int* __restrict__ dst,
    int* __restrict__ cursor, int* __restrict__ sorted_src, int E)
{
    int i = blockIdx.x * blockDim.x + threadIdx.x;
    if (i < E) {
        int d = dst[i];
        int pos = atomicAdd(&cursor[d], 1);
        sorted_src[pos] = src[i];
    }
}

// K5: one wave per dst node: segment softmax + weighted aggregate + finalize.
__global__ void __launch_bounds__(256) k_gat(
    const int* __restrict__ rowptr, const int* __restrict__ sorted_src,
    const float* __restrict__ al_s, const float* __restrict__ al_d,
    const float* __restrict__ hbuf, const float* __restrict__ bias,
    float* __restrict__ out, int N)
{
    __shared__ int   s_src[WAVES_PER_BLOCK][64];
    __shared__ float s_ex[WAVES_PER_BLOCK][64][9];   // pad 8->9: stride coprime w/ 32 banks
    __shared__ float s_out[WAVES_PER_BLOCK][NHC];
    __shared__ float s_v[WAVES_PER_BLOCK][NC];

    int wid  = threadIdx.x >> 6;
    int lane = threadIdx.x & 63;
    int n = blockIdx.x * WAVES_PER_BLOCK + wid;
    if (n >= N) return;                         // uniform per wave

    int base  = rowptr[n];
    int total = rowptr[n + 1] - base + 1;       // + implicit self-loop (virtual idx total-1)

    float ald[8];
    load8(ald, al_d + (size_t)n * NHEADS);

    float m[NHEADS], den[NHEADS];
    #pragma unroll
    for (int h = 0; h < NHEADS; ++h) { m[h] = -INFINITY; den[h] = 0.f; }

    int own0 = lane;            // output element 0..63
    int own1 = 64 + lane;       // valid for lane<8 (elements 64..71)
    int h0 = own0 / NC;
    int h1 = own1 / NC;         // == 7 for lane<8
    float acc0 = 0.f, acc1 = 0.f;

    if (total <= 64) {
        // ---- fast path: whole segment fits one wave-chunk; logits stay in regs ----
        int idx = lane;
        bool act = idx < total;
        int s = n;
        float lg[NHEADS];
        if (act) {
            if (idx != total - 1) s = sorted_src[base + idx];
            float als[8];
            load8(als, al_s + (size_t)s * NHEADS);
            #pragma unroll
            for (int h = 0; h < NHEADS; ++h) lg[h] = lrelu(als[h] + ald[h]);
        } else {
            #pragma unroll
            for (int h = 0; h < NHEADS; ++h) lg[h] = -INFINITY;
        }
        #pragma unroll
        for (int h = 0; h < NHEADS; ++h) {
            float v = lg[h];
            #pragma unroll
            for (int mask = 1; mask < 64; mask <<= 1)
                v = fmaxf(v, __shfl_xor(v, mask, 64));
            m[h] = v;
        }
        float ex[NHEADS];
        #pragma unroll
        for (int h = 0; h < NHEADS; ++h) {
            ex[h] = act ? expf(lg[h] - m[h]) : 0.f;
            float v = ex[h];
            #pragma unroll
            for (int mask = 1; mask < 64; mask <<= 1)
                v += __shfl_xor(v, mask, 64);
            den[h] = v;
        }
        s_src[wid][lane] = s;
        #pragma unroll
        for (int h = 0; h < NHEADS; ++h) s_ex[wid][lane][h] = ex[h];
        int cnt = total;
        for (int e = 0; e < cnt; ++e) {
            int se = s_src[wid][e];
            const float* hr = hbuf + (size_t)se * NHC;
            float e0 = s_ex[wid][e][h0];
            acc0 = fmaf(e0, hr[own0], acc0);
            if (lane < NHC - 64) {
                float e1 = s_ex[wid][e][h1];
                acc1 = fmaf(e1, hr[own1], acc1);
            }
        }
    } else {
        // ---- generic chunked path (rare: deg >= 64) ----
        for (int st = 0; st < total; st += 64) {
            int idx = st + lane;
            if (idx < total) {
                int s = (idx == total - 1) ? n : sorted_src[base + idx];
                float als[8];
                load8(als, al_s + (size_t)s * NHEADS);
                #pragma unroll
                for (int h = 0; h < NHEADS; ++h)
                    m[h] = fmaxf(m[h], lrelu(als[h] + ald[h]));
            }
        }
        #pragma unroll
        for (int h = 0; h < NHEADS; ++h) {
            float v = m[h];
            #pragma unroll
            for (int mask = 1; mask < 64; mask <<= 1)
                v = fmaxf(v, __shfl_xor(v, mask, 64));
            m[h] = v;
        }
        for (int st = 0; st < total; st += 64) {
            int cnt = min(64, total - st);
            int idx = st + lane;
            int s = n;
            float ex[NHEADS];
            if (idx < total) {
                if (idx != total - 1) s = sorted_src[base + idx];
                float als[8];
                load8(als, al_s + (size_t)s * NHEADS);
                #pragma unroll
                for (int h = 0; h < NHEADS; ++h)
                    ex[h] = expf(lrelu(als[h] + ald[h]) - m[h]);
            } else {
                #pragma unroll
                for (int h = 0; h < NHEADS; ++h) ex[h] = 0.f;
            }
            #pragma unroll
            for (int h = 0; h < NHEADS; ++h) {
                float v = ex[h];
                #pragma unroll
                for (int mask = 1; mask < 64; mask <<= 1)
                    v += __shfl_xor(v, mask, 64);
                den[h] += v;
            }
            s_src[wid][lane] = s;
            #pragma unroll
            for (int h = 0; h < NHEADS; ++h) s_ex[wid][lane][h] = ex[h];
            for (int e = 0; e < cnt; ++e) {
                int se = s_src[wid][e];
                const float* hr = hbuf + (size_t)se * NHC;
                float e0 = s_ex[wid][e][h0];
                acc0 = fmaf(e0, hr[own0], acc0);
                if (lane < NHC - 64) {
                    float e1 = s_ex[wid][e][h1];
                    acc1 = fmaf(e1, hr[own1], acc1);
                }
            }
        }
    }

    // ---- finalize: normalize, head-mean, bias, log-softmax ----
    s_out[wid][own0] = acc0 / (den[h0] + 1e-16f);
    if (lane < NHC - 64) s_out[wid][own1] = acc1 / (den[h1] + 1e-16f);

    if (lane < NC) {
        float v = 0.f;
        #pragma unroll
        for (int h = 0; h < NHEADS; ++h) v += s_out[wid][h * NC + lane];
        v = v * (1.f / NHEADS) + bias[lane];
        s_v[wid][lane] = v;
    }
    if (lane < NC) {
        float mx = -INFINITY;
        #pragma unroll
        for (int c = 0; c < NC; ++c) mx = fmaxf(mx, s_v[wid][c]);
        float sum = 0.f;
        #pragma unroll
        for (int c = 0; c < NC; ++c) sum += expf(s_v[wid][c] - mx);
        float lse = mx + logf(sum);
        out[(size_t)n * NC + lane] = s_v[wid][lane] - lse;
    }
}

extern "C" void kernel_launch(void* const* d_in, const int* in_sizes, int n_in,
                              void* d_out, int out_size, void* d_ws, size_t ws_size,
                              hipStream_t stream)
{
    const float* x     = (const float*)d_in[0];
    const int*   ei    = (const int*)d_in[1];
    const float* W     = (const float*)d_in[2];
    const float* a_src = (const float*)d_in[3];
    const float* a_dst = (const float*)d_in[4];
    const float* bias  = (const float*)d_in[5];

    int N = in_sizes[0] / FIN;   // 100000
    int E = in_sizes[1] / 2;     // 1600000
    const int* src = ei;
    const int* dst = ei + E;

    char* ws = (char*)d_ws;
    float* hbuf = (float*)ws;       ws += (size_t)N * NHC * sizeof(float);
    float* al_s = (float*)ws;       ws += (size_t)N * NHEADS * sizeof(float);
    float* al_d = (float*)ws;       ws += (size_t)N * NHEADS * sizeof(float);
    int* deg    = (int*)ws;         ws += (size_t)N * sizeof(int);
    int* rowptr = (int*)ws;         ws += (size_t)(N + 1) * sizeof(int);
    int* cursor = (int*)ws;         ws += (size_t)N * sizeof(int);
    int* sorted_src = (int*)ws;     ws += (size_t)E * sizeof(int);

    hipMemsetAsync(deg, 0, (size_t)N * sizeof(int), stream);

    int nb_n = (N + 255) / 256;
    int nb_e = (E + 255) / 256;
    k_transform<<<nb_n, 256, 0, stream>>>(x, W, a_src, a_dst, hbuf, al_s, al_d, N);
    k_degree<<<nb_e, 256, 0, stream>>>(dst, deg, E);
    k_scan<<<1, SCAN_T, 0, stream>>>(deg, rowptr, cursor, N);
    k_scatter<<<nb_e, 256, 0, stream>>>(src, dst, cursor, sorted_src, E);

    int nb_g = (N + WAVES_PER_BLOCK - 1) / WAVES_PER_BLOCK;
    k_gat<<<nb_g, 256, 0, stream>>>(rowptr, sorted_src, al_s, al_d, hbuf, bias,
                                    (float*)d_out, N);
}

// Round 3
// 456.872 us; speedup vs baseline: 16.3525x; 1.4804x over previous
//
#include <hip/hip_runtime.h>
#include <math.h>

#define NHEADS 8
#define NC 9
#define NHC 72
#define FIN 12
#define WAVES_PER_BLOCK 4
#define PF 8            // aggregation prefetch depth (static-indexed regs)
#define CHUNK 2048      // scan chunk per block (256 thr x 8)

__device__ __forceinline__ float lrelu(float v) { return v > 0.f ? v : 0.2f * v; }

__device__ __forceinline__ void load8(float* v, const float* p) {
    const float4* q = reinterpret_cast<const float4*>(p);
    float4 a = q[0], b = q[1];
    v[0]=a.x; v[1]=a.y; v[2]=a.z; v[3]=a.w;
    v[4]=b.x; v[5]=b.y; v[6]=b.z; v[7]=b.w;
}

// K1: per-node linear transform + attention halves.
__global__ void __launch_bounds__(256) k_transform(
    const float* __restrict__ x, const float* __restrict__ W,
    const float* __restrict__ a_src, const float* __restrict__ a_dst,
    float* __restrict__ hbuf, float* __restrict__ al_s, float* __restrict__ al_d,
    int N)
{
    __shared__ float sW[FIN * NHC];
    __shared__ float sas[NHC];
    __shared__ float sad[NHC];
    int tid = threadIdx.x;
    for (int i = tid; i < FIN * NHC; i += blockDim.x) sW[i] = W[i];
    if (tid < NHC) { sas[tid] = a_src[tid]; sad[tid] = a_dst[tid]; }
    __syncthreads();
    int n = blockIdx.x * blockDim.x + tid;
    if (n >= N) return;

    float xv[FIN];
    const float4* xp = reinterpret_cast<const float4*>(x + (size_t)n * FIN);
    float4 q0 = xp[0], q1 = xp[1], q2 = xp[2];
    xv[0] = q0.x; xv[1] = q0.y; xv[2] = q0.z; xv[3] = q0.w;
    xv[4] = q1.x; xv[5] = q1.y; xv[6] = q1.z; xv[7] = q1.w;
    xv[8] = q2.x; xv[9] = q2.y; xv[10] = q2.z; xv[11] = q2.w;

    float acc[NHC];
    #pragma unroll
    for (int j = 0; j < NHC; ++j) acc[j] = 0.f;
    #pragma unroll
    for (int k = 0; k < FIN; ++k) {
        float xk = xv[k];
        #pragma unroll
        for (int j = 0; j < NHC; ++j) acc[j] = fmaf(xk, sW[k * NHC + j], acc[j]);
    }

    float* hp = hbuf + (size_t)n * NHC;
    #pragma unroll
    for (int j = 0; j < NHC; ++j) hp[j] = acc[j];

    #pragma unroll
    for (int hh = 0; hh < NHEADS; ++hh) {
        float ss = 0.f, dd = 0.f;
        #pragma unroll
        for (int c = 0; c < NC; ++c) {
            ss = fmaf(acc[hh * NC + c], sas[hh * NC + c], ss);
            dd = fmaf(acc[hh * NC + c], sad[hh * NC + c], dd);
        }
        al_s[(size_t)n * NHEADS + hh] = ss;
        al_d[(size_t)n * NHEADS + hh] = dd;
    }
}

// K2: in-degree count (real edges only; self-loops implicit).
__global__ void __launch_bounds__(256) k_degree(
    const int* __restrict__ dst, int* __restrict__ deg, int E)
{
    int i = blockIdx.x * blockDim.x + threadIdx.x;
    if (i < E) atomicAdd(&deg[dst[i]], 1);
}

// K3a: per-block partial sums of deg over CHUNK-sized tiles.
__global__ void __launch_bounds__(256) k_scanA(
    const int* __restrict__ deg, int* __restrict__ bsum, int N)
{
    __shared__ int red[256];
    int t = threadIdx.x;
    int start = blockIdx.x * CHUNK + t * 8;
    int s = 0;
    if (start + 8 <= N) {
        const int4* p = reinterpret_cast<const int4*>(deg + start);
        int4 a = p[0], b = p[1];
        s = a.x + a.y + a.z + a.w + b.x + b.y + b.z + b.w;
    } else {
        for (int i = start; i < N; ++i) s += deg[i];
    }
    red[t] = s;
    __syncthreads();
    for (int off = 128; off > 0; off >>= 1) {
        if (t < off) red[t] += red[t + off];
        __syncthreads();
    }
    if (t == 0) bsum[blockIdx.x] = red[0];
}

// K3b: scan the (<=64) block sums with one wave; also writes rowptr[N].
__global__ void __launch_bounds__(64) k_scanB(
    const int* __restrict__ bsum, int* __restrict__ bpre,
    int* __restrict__ rowptr, int NB, int N)
{
    int lane = threadIdx.x;
    int own = (lane < NB) ? bsum[lane] : 0;
    int val = own;
    #pragma unroll
    for (int off = 1; off < 64; off <<= 1) {
        int v = __shfl_up(val, off, 64);
        if (lane >= off) val += v;
    }
    if (lane < NB) bpre[lane] = val - own;   // exclusive prefix
    int total = __shfl(val, 63, 64);
    if (lane == 0) rowptr[N] = total;
}

// K3c: apply — write rowptr/cursor per element.
__global__ void __launch_bounds__(256) k_scanC(
    const int* __restrict__ deg, const int* __restrict__ bpre,
    int* __restrict__ rowptr, int* __restrict__ cursor, int N)
{
    __shared__ int pre[256];
    int t = threadIdx.x;
    int start = blockIdx.x * CHUNK + t * 8;
    int d[8];
    int s = 0;
    if (start + 8 <= N) {
        const int4* p = reinterpret_cast<const int4*>(deg + start);
        int4 a = p[0], b = p[1];
        d[0]=a.x; d[1]=a.y; d[2]=a.z; d[3]=a.w;
        d[4]=b.x; d[5]=b.y; d[6]=b.z; d[7]=b.w;
        s = d[0]+d[1]+d[2]+d[3]+d[4]+d[5]+d[6]+d[7];
    } else {
        #pragma unroll
        for (int j = 0; j < 8; ++j) {
            d[j] = (start + j < N) ? deg[start + j] : 0;
            s += d[j];
        }
    }
    pre[t] = s;
    __syncthreads();
    // Hillis-Steele inclusive scan over 256 thread sums
    for (int off = 1; off < 256; off <<= 1) {
        int v = (t >= off) ? pre[t - off] : 0;
        __syncthreads();
        pre[t] += v;
        __syncthreads();
    }
    int run = bpre[blockIdx.x] + ((t == 0) ? 0 : pre[t - 1]);
    #pragma unroll
    for (int j = 0; j < 8; ++j) {
        int i = start + j;
        if (i < N) {
            rowptr[i] = run;
            cursor[i] = run;
            run += d[j];
        }
    }
}

// K4: scatter edge src indices into CSR slots.
__global__ void __launch_bounds__(256) k_scatter(
    const int* __restrict__ src, const int* __restrict__ dst,
    int* __restrict__ cursor, int* __restrict__ sorted_src, int E)
{
    int i = blockIdx.x * blockDim.x + threadIdx.x;
    if (i < E) {
        int d = dst[i];
        int pos = atomicAdd(&cursor[d], 1);
        sorted_src[pos] = src[i];
    }
}

// K5: one wave per dst node: segment softmax + weighted aggregate + finalize.
__global__ void __launch_bounds__(256) k_gat(
    const int* __restrict__ rowptr, const int* __restrict__ sorted_src,
    const float* __restrict__ al_s, const float* __restrict__ al_d,
    const float* __restrict__ hbuf, const float* __restrict__ bias,
    float* __restrict__ out, int N)
{
    __shared__ int   s_src[WAVES_PER_BLOCK][64];
    __shared__ float s_ex[WAVES_PER_BLOCK][64][9];   // pad 8->9: stride coprime w/ 32 banks
    __shared__ float s_out[WAVES_PER_BLOCK][NHC];
    __shared__ float s_v[WAVES_PER_BLOCK][NC];

    int wid  = threadIdx.x >> 6;
    int lane = threadIdx.x & 63;
    int n = blockIdx.x * WAVES_PER_BLOCK + wid;
    if (n >= N) return;                         // uniform per wave

    int base  = rowptr[n];
    int total = rowptr[n + 1] - base + 1;       // + implicit self-loop (virtual idx total-1)

    float ald[8];
    load8(ald, al_d + (size_t)n * NHEADS);

    int own0 = lane;            // output element 0..63
    int own1 = 64 + lane;       // valid for lane<8 (elements 64..71)
    int h0 = own0 / NC;
    int h1 = own1 / NC;         // == 7 for lane<8
    float acc0 = 0.f, acc1 = 0.f;
    float den[NHEADS];

    if (total <= 64) {
        // ---- fast path: whole segment fits one wave-chunk ----
        int idx = lane;
        bool act = idx < total;
        int s = n;
        if (act && idx != total - 1) s = sorted_src[base + idx];
        s_src[wid][lane] = s;

        float als[8];
        load8(als, al_s + (size_t)s * NHEADS);

        int cnt = total;
        // issue first PF h-row loads NOW; latency hides under the butterflies
        float ph0[PF], ph1[PF];
        #pragma unroll
        for (int p = 0; p < PF; ++p) {
            if (p < cnt) {
                int se = s_src[wid][p];
                const float* hr = hbuf + (size_t)se * NHC;
                ph0[p] = hr[own0];
                ph1[p] = (lane < NHC - 64) ? hr[own1] : 0.f;
            } else { ph0[p] = 0.f; ph1[p] = 0.f; }
        }

        float lg[NHEADS];
        #pragma unroll
        for (int h = 0; h < NHEADS; ++h)
            lg[h] = act ? lrelu(als[h] + ald[h]) : -INFINITY;

        float m[NHEADS];
        #pragma unroll
        for (int h = 0; h < NHEADS; ++h) {
            float v = lg[h];
            #pragma unroll
            for (int mask = 1; mask < 64; mask <<= 1)
                v = fmaxf(v, __shfl_xor(v, mask, 64));
            m[h] = v;
        }
        float ex[NHEADS];
        #pragma unroll
        for (int h = 0; h < NHEADS; ++h) {
            ex[h] = expf(lg[h] - m[h]);            // inactive lanes: exp(-inf)=0
            float v = ex[h];
            #pragma unroll
            for (int mask = 1; mask < 64; mask <<= 1)
                v += __shfl_xor(v, mask, 64);
            den[h] = v;
        }
        #pragma unroll
        for (int h = 0; h < NHEADS; ++h) s_ex[wid][lane][h] = ex[h];

        // ---- pipelined aggregation: PF loads in flight, static reg indices ----
        for (int b0 = 0; b0 < cnt; b0 += PF) {
            #pragma unroll
            for (int p = 0; p < PF; ++p) {
                int e = b0 + p;
                if (e < cnt) {
                    acc0 = fmaf(s_ex[wid][e][h0], ph0[p], acc0);
                    if (lane < NHC - 64)
                        acc1 = fmaf(s_ex[wid][e][h1], ph1[p], acc1);
                    int np = e + PF;
                    if (np < cnt) {
                        int se = s_src[wid][np];
                        const float* hr = hbuf + (size_t)se * NHC;
                        ph0[p] = hr[own0];
                        ph1[p] = (lane < NHC - 64) ? hr[own1] : 0.f;
                    }
                }
            }
        }
    } else {
        // ---- generic chunked path (deg >= 64; effectively never for this input) ----
        float m[NHEADS];
        #pragma unroll
        for (int h = 0; h < NHEADS; ++h) { m[h] = -INFINITY; den[h] = 0.f; }
        for (int st = 0; st < total; st += 64) {
            int idx = st + lane;
            if (idx < total) {
                int s = (idx == total - 1) ? n : sorted_src[base + idx];
                float als[8];
                load8(als, al_s + (size_t)s * NHEADS);
                #pragma unroll
                for (int h = 0; h < NHEADS; ++h)
                    m[h] = fmaxf(m[h], lrelu(als[h] + ald[h]));
            }
        }
        #pragma unroll
        for (int h = 0; h < NHEADS; ++h) {
            float v = m[h];
            #pragma unroll
            for (int mask = 1; mask < 64; mask <<= 1)
                v = fmaxf(v, __shfl_xor(v, mask, 64));
            m[h] = v;
        }
        for (int st = 0; st < total; st += 64) {
            int cnt = min(64, total - st);
            int idx = st + lane;
            int s = n;
            float ex[NHEADS];
            if (idx < total) {
                if (idx != total - 1) s = sorted_src[base + idx];
                float als[8];
                load8(als, al_s + (size_t)s * NHEADS);
                #pragma unroll
                for (int h = 0; h < NHEADS; ++h)
                    ex[h] = expf(lrelu(als[h] + ald[h]) - m[h]);
            } else {
                #pragma unroll
                for (int h = 0; h < NHEADS; ++h) ex[h] = 0.f;
            }
            #pragma unroll
            for (int h = 0; h < NHEADS; ++h) {
                float v = ex[h];
                #pragma unroll
                for (int mask = 1; mask < 64; mask <<= 1)
                    v += __shfl_xor(v, mask, 64);
                den[h] += v;
            }
            s_src[wid][lane] = s;
            #pragma unroll
            for (int h = 0; h < NHEADS; ++h) s_ex[wid][lane][h] = ex[h];
            for (int e = 0; e < cnt; ++e) {
                int se = s_src[wid][e];
                const float* hr = hbuf + (size_t)se * NHC;
                acc0 = fmaf(s_ex[wid][e][h0], hr[own0], acc0);
                if (lane < NHC - 64)
                    acc1 = fmaf(s_ex[wid][e][h1], hr[own1], acc1);
            }
        }
    }

    // ---- finalize: normalize, head-mean, bias, log-softmax ----
    s_out[wid][own0] = acc0 / (den[h0] + 1e-16f);
    if (lane < NHC - 64) s_out[wid][own1] = acc1 / (den[h1] + 1e-16f);

    if (lane < NC) {
        float v = 0.f;
        #pragma unroll
        for (int h = 0; h < NHEADS; ++h) v += s_out[wid][h * NC + lane];
        v = v * (1.f / NHEADS) + bias[lane];
        s_v[wid][lane] = v;
    }
    if (lane < NC) {
        float mx = -INFINITY;
        #pragma unroll
        for (int c = 0; c < NC; ++c) mx = fmaxf(mx, s_v[wid][c]);
        float sum = 0.f;
        #pragma unroll
        for (int c = 0; c < NC; ++c) sum += expf(s_v[wid][c] - mx);
        float lse = mx + logf(sum);
        out[(size_t)n * NC + lane] = s_v[wid][lane] - lse;
    }
}

extern "C" void kernel_launch(void* const* d_in, const int* in_sizes, int n_in,
                              void* d_out, int out_size, void* d_ws, size_t ws_size,
                              hipStream_t stream)
{
    const float* x     = (const float*)d_in[0];
    const int*   ei    = (const int*)d_in[1];
    const float* W     = (const float*)d_in[2];
    const float* a_src = (const float*)d_in[3];
    const float* a_dst = (const float*)d_in[4];
    const float* bias  = (const float*)d_in[5];

    int N = in_sizes[0] / FIN;   // 100000
    int E = in_sizes[1] / 2;     // 1600000
    const int* src = ei;
    const int* dst = ei + E;

    char* ws = (char*)d_ws;
    float* hbuf = (float*)ws;       ws += (size_t)N * NHC * sizeof(float);
    float* al_s = (float*)ws;       ws += (size_t)N * NHEADS * sizeof(float);
    float* al_d = (float*)ws;       ws += (size_t)N * NHEADS * sizeof(float);
    int* deg    = (int*)ws;         ws += (size_t)N * sizeof(int);
    int* rowptr = (int*)ws;         ws += (size_t)(N + 1) * sizeof(int);
    int* cursor = (int*)ws;         ws += (size_t)N * sizeof(int);
    int* bsum   = (int*)ws;         ws += 64 * sizeof(int);
    int* bpre   = (int*)ws;         ws += 64 * sizeof(int);
    int* sorted_src = (int*)ws;     ws += (size_t)E * sizeof(int);

    hipMemsetAsync(deg, 0, (size_t)N * sizeof(int), stream);

    int nb_n = (N + 255) / 256;
    int nb_e = (E + 255) / 256;
    int NB   = (N + CHUNK - 1) / CHUNK;   // 49 for N=100000 (must be <= 64)

    k_transform<<<nb_n, 256, 0, stream>>>(x, W, a_src, a_dst, hbuf, al_s, al_d, N);
    k_degree<<<nb_e, 256, 0, stream>>>(dst, deg, E);
    k_scanA<<<NB, 256, 0, stream>>>(deg, bsum, N);
    k_scanB<<<1, 64, 0, stream>>>(bsum, bpre, rowptr, NB, N);
    k_scanC<<<NB, 256, 0, stream>>>(deg, bpre, rowptr, cursor, N);
    k_scatter<<<nb_e, 256, 0, stream>>>(src, dst, cursor, sorted_src, E);

    int nb_g = (N + WAVES_PER_BLOCK - 1) / WAVES_PER_BLOCK;
    k_gat<<<nb_g, 256, 0, stream>>>(rowptr, sorted_src, al_s, al_d, hbuf, bias,
                                    (float*)d_out, N);
}

// Round 4
// 300.711 us; speedup vs baseline: 24.8445x; 1.5193x over previous
//
#include <hip/hip_runtime.h>
#include <math.h>

#define NHEADS 8
#define NC 9
#define NHC 72
#define FIN 12
#define WAVES_PER_BLOCK 4
#define CHUNK 2048      // scan chunk per block (256 thr x 8)
#define ROWW 48         // words per node row: 36 (72 bf16) + 8 (al_s f32) + 4 pad = 192 B
#define ALS_OFF 36      // word offset of al_s within row

__device__ __forceinline__ float lrelu(float v) { return v > 0.f ? v : 0.2f * v; }

// round-to-nearest-even bf16 pack of two floats into one uint (a=low, b=high)
__device__ __forceinline__ unsigned pack_bf16(float a, float b) {
    unsigned ua = __float_as_uint(a); ua += 0x7fffu + ((ua >> 16) & 1u);
    unsigned ub = __float_as_uint(b); ub += 0x7fffu + ((ub >> 16) & 1u);
    return (ua >> 16) | (ub & 0xffff0000u);
}

// K1: per-node linear transform -> packed bf16 row [h | al_s]; al_d separate.
// Fused tail: in-degree count over edges (grid-stride).
__global__ void __launch_bounds__(256) k_transform(
    const float* __restrict__ x, const float* __restrict__ W,
    const float* __restrict__ a_src, const float* __restrict__ a_dst,
    unsigned* __restrict__ hrow, float* __restrict__ al_d,
    const int* __restrict__ dst, int* __restrict__ deg, int N, int E)
{
    __shared__ float sW[FIN * NHC];
    __shared__ float sas[NHC];
    __shared__ float sad[NHC];
    int tid = threadIdx.x;
    for (int i = tid; i < FIN * NHC; i += blockDim.x) sW[i] = W[i];
    if (tid < NHC) { sas[tid] = a_src[tid]; sad[tid] = a_dst[tid]; }
    __syncthreads();
    int n = blockIdx.x * blockDim.x + tid;
    if (n < N) {
        float xv[FIN];
        const float4* xp = reinterpret_cast<const float4*>(x + (size_t)n * FIN);
        float4 q0 = xp[0], q1 = xp[1], q2 = xp[2];
        xv[0] = q0.x; xv[1] = q0.y; xv[2] = q0.z; xv[3] = q0.w;
        xv[4] = q1.x; xv[5] = q1.y; xv[6] = q1.z; xv[7] = q1.w;
        xv[8] = q2.x; xv[9] = q2.y; xv[10] = q2.z; xv[11] = q2.w;

        float acc[NHC];
        #pragma unroll
        for (int j = 0; j < NHC; ++j) acc[j] = 0.f;
        #pragma unroll
        for (int k = 0; k < FIN; ++k) {
            float xk = xv[k];
            #pragma unroll
            for (int j = 0; j < NHC; ++j) acc[j] = fmaf(xk, sW[k * NHC + j], acc[j]);
        }

        unsigned* rp = hrow + (size_t)n * ROWW;
        #pragma unroll
        for (int l = 0; l < NHC / 2; ++l)
            rp[l] = pack_bf16(acc[2 * l], acc[2 * l + 1]);

        float* rf = reinterpret_cast<float*>(rp);
        #pragma unroll
        for (int hh = 0; hh < NHEADS; ++hh) {
            float ss = 0.f, dd = 0.f;
            #pragma unroll
            for (int c = 0; c < NC; ++c) {
                ss = fmaf(acc[hh * NC + c], sas[hh * NC + c], ss);
                dd = fmaf(acc[hh * NC + c], sad[hh * NC + c], dd);
            }
            rf[ALS_OFF + hh] = ss;
            al_d[(size_t)n * NHEADS + hh] = dd;
        }
    }
    // fused degree count
    int stride = gridDim.x * blockDim.x;
    for (int i = blockIdx.x * blockDim.x + tid; i < E; i += stride)
        atomicAdd(&deg[dst[i]], 1);
}

// K3a: per-block partial sums of deg over CHUNK-sized tiles.
__global__ void __launch_bounds__(256) k_scanA(
    const int* __restrict__ deg, int* __restrict__ bsum, int N)
{
    __shared__ int red[256];
    int t = threadIdx.x;
    int start = blockIdx.x * CHUNK + t * 8;
    int s = 0;
    if (start + 8 <= N) {
        const int4* p = reinterpret_cast<const int4*>(deg + start);
        int4 a = p[0], b = p[1];
        s = a.x + a.y + a.z + a.w + b.x + b.y + b.z + b.w;
    } else {
        for (int i = start; i < N; ++i) s += deg[i];
    }
    red[t] = s;
    __syncthreads();
    for (int off = 128; off > 0; off >>= 1) {
        if (t < off) red[t] += red[t + off];
        __syncthreads();
    }
    if (t == 0) bsum[blockIdx.x] = red[0];
}

// K3b: scan the (<=64) block sums with one wave; also writes rowptr[N].
__global__ void __launch_bounds__(64) k_scanB(
    const int* __restrict__ bsum, int* __restrict__ bpre,
    int* __restrict__ rowptr, int NB, int N)
{
    int lane = threadIdx.x;
    int own = (lane < NB) ? bsum[lane] : 0;
    int val = own;
    #pragma unroll
    for (int off = 1; off < 64; off <<= 1) {
        int v = __shfl_up(val, off, 64);
        if (lane >= off) val += v;
    }
    if (lane < NB) bpre[lane] = val - own;   // exclusive prefix
    int total = __shfl(val, 63, 64);
    if (lane == 0) rowptr[N] = total;
}

// K3c: apply — write rowptr/cursor per element.
__global__ void __launch_bounds__(256) k_scanC(
    const int* __restrict__ deg, const int* __restrict__ bpre,
    int* __restrict__ rowptr, int* __restrict__ cursor, int N)
{
    __shared__ int pre[256];
    int t = threadIdx.x;
    int start = blockIdx.x * CHUNK + t * 8;
    int d[8];
    int s = 0;
    if (start + 8 <= N) {
        const int4* p = reinterpret_cast<const int4*>(deg + start);
        int4 a = p[0], b = p[1];
        d[0]=a.x; d[1]=a.y; d[2]=a.z; d[3]=a.w;
        d[4]=b.x; d[5]=b.y; d[6]=b.z; d[7]=b.w;
        s = d[0]+d[1]+d[2]+d[3]+d[4]+d[5]+d[6]+d[7];
    } else {
        #pragma unroll
        for (int j = 0; j < 8; ++j) {
            d[j] = (start + j < N) ? deg[start + j] : 0;
            s += d[j];
        }
    }
    pre[t] = s;
    __syncthreads();
    for (int off = 1; off < 256; off <<= 1) {
        int v = (t >= off) ? pre[t - off] : 0;
        __syncthreads();
        pre[t] += v;
        __syncthreads();
    }
    int run = bpre[blockIdx.x] + ((t == 0) ? 0 : pre[t - 1]);
    #pragma unroll
    for (int j = 0; j < 8; ++j) {
        int i = start + j;
        if (i < N) {
            rowptr[i] = run;
            cursor[i] = run;
            run += d[j];
        }
    }
}

// K4: scatter edge src indices into CSR slots.
__global__ void __launch_bounds__(256) k_scatter(
    const int* __restrict__ src, const int* __restrict__ dst,
    int* __restrict__ cursor, int* __restrict__ sorted_src, int E)
{
    int i = blockIdx.x * blockDim.x + threadIdx.x;
    if (i < E) {
        int d = dst[i];
        int pos = atomicAdd(&cursor[d], 1);
        sorted_src[pos] = src[i];
    }
}

// K5: one wave per dst node: no-max segment softmax + bf16 gather-aggregate + finalize.
__global__ void __launch_bounds__(256) k_gat(
    const int* __restrict__ rowptr, const int* __restrict__ sorted_src,
    const unsigned* __restrict__ hrow, const float* __restrict__ al_d,
    const float* __restrict__ bias, float* __restrict__ out, int N)
{
    __shared__ int   s_off[WAVES_PER_BLOCK][64];     // row BYTE offsets
    __shared__ float s_ex[WAVES_PER_BLOCK][64][9];   // [edge][head], pad 8->9
    __shared__ float s_den[WAVES_PER_BLOCK][8];
    __shared__ float s_out[WAVES_PER_BLOCK][NHC];
    __shared__ float s_v[WAVES_PER_BLOCK][NC];

    int wid  = threadIdx.x >> 6;
    int lane = threadIdx.x & 63;
    int n = blockIdx.x * WAVES_PER_BLOCK + wid;
    if (n >= N) return;                         // uniform per wave

    int base  = rowptr[n];
    int total = rowptr[n + 1] - base + 1;       // + implicit self-loop at index total-1

    int g  = lane >> 3;                         // edge-slot group (softmax phase)
    int hh = lane & 7;                          // head (softmax phase)
    float ald_h = al_d[(size_t)n * NHEADS + hh];

    bool act36 = lane < NHC / 2;
    int widx4 = act36 ? lane * 4 : 0;           // payload word byte-offset within row
    int c0 = 2 * lane, c1 = 2 * lane + 1;
    int ha = act36 ? c0 / NC : 0;
    int hb = act36 ? c1 / NC : 0;
    float accA = 0.f, accB = 0.f;
    float den_part = 0.f;

    const char* hbase = reinterpret_cast<const char*>(hrow);
    int als_boff = (ALS_OFF + hh) * 4;          // byte offset of my head's al_s in a row

    for (int cb = 0; cb < total; cb += 64) {
        int rem = total - cb;
        int clen = rem < 64 ? rem : 64;
        int clenR = (clen + 3) & ~3;            // guard-free round-up (<=64)

        // fill row byte-offsets for this chunk (j >= total-1 -> self row n; safe pad)
        int j = cb + lane;
        int s = n;
        if (j < total - 1) s = sorted_src[base + j];
        s_off[wid][lane] = s * (ROWW * 4);

        // softmax phase: lane (g,hh) handles local edges lj = k*8+g for head hh
        for (int k = 0; k * 8 < clenR; ++k) {
            int lj = k * 8 + g;
            int off = s_off[wid][lj];
            float als = *reinterpret_cast<const float*>(hbase + off + als_boff);
            float ex = 0.f;
            if (cb + lj < total) ex = __expf(lrelu(als + ald_h));
            s_ex[wid][lj][hh] = ex;
            den_part += ex;
        }

        // aggregation phase: guard-free, unrolled by 4
        for (int e = 0; e < clenR; e += 4) {
            #pragma unroll
            for (int p = 0; p < 4; ++p) {
                int ee = e + p;
                int off = s_off[wid][ee];
                unsigned w = *reinterpret_cast<const unsigned*>(hbase + off + widx4);
                float fa = __uint_as_float(w << 16);
                float fb = __uint_as_float(w & 0xffff0000u);
                accA = fmaf(s_ex[wid][ee][ha], fa, accA);
                accB = fmaf(s_ex[wid][ee][hb], fb, accB);
            }
        }
    }

    // denominator: 3-shuffle reduce across the 8 lanes sharing each head
    den_part += __shfl_xor(den_part, 8, 64);
    den_part += __shfl_xor(den_part, 16, 64);
    den_part += __shfl_xor(den_part, 32, 64);
    if (lane < 8) s_den[wid][lane] = den_part;

    if (act36) {
        float ia = 1.f / (s_den[wid][ha] + 1e-16f);
        float ib = 1.f / (s_den[wid][hb] + 1e-16f);
        s_out[wid][c0] = accA * ia;
        s_out[wid][c1] = accB * ib;
    }

    if (lane < NC) {
        float v = 0.f;
        #pragma unroll
        for (int h = 0; h < NHEADS; ++h) v += s_out[wid][h * NC + lane];
        v = v * (1.f / NHEADS) + bias[lane];
        s_v[wid][lane] = v;
        float mx = -INFINITY;
        #pragma unroll
        for (int c = 0; c < NC; ++c) mx = fmaxf(mx, s_v[wid][c]);
        float sum = 0.f;
        #pragma unroll
        for (int c = 0; c < NC; ++c) sum += __expf(s_v[wid][c] - mx);
        float lse = mx + __logf(sum);
        out[(size_t)n * NC + lane] = s_v[wid][lane] - lse;
    }
}

extern "C" void kernel_launch(void* const* d_in, const int* in_sizes, int n_in,
                              void* d_out, int out_size, void* d_ws, size_t ws_size,
                              hipStream_t stream)
{
    const float* x     = (const float*)d_in[0];
    const int*   ei    = (const int*)d_in[1];
    const float* W     = (const float*)d_in[2];
    const float* a_src = (const float*)d_in[3];
    const float* a_dst = (const float*)d_in[4];
    const float* bias  = (const float*)d_in[5];

    int N = in_sizes[0] / FIN;   // 100000
    int E = in_sizes[1] / 2;     // 1600000
    const int* src = ei;
    const int* dst = ei + E;

    char* ws = (char*)d_ws;
    unsigned* hrow = (unsigned*)ws; ws += (size_t)N * ROWW * sizeof(unsigned);
    float* al_d = (float*)ws;       ws += (size_t)N * NHEADS * sizeof(float);
    int* deg    = (int*)ws;         ws += (size_t)N * sizeof(int);
    int* rowptr = (int*)ws;         ws += (size_t)(N + 1) * sizeof(int);
    int* cursor = (int*)ws;         ws += (size_t)N * sizeof(int);
    int* bsum   = (int*)ws;         ws += 64 * sizeof(int);
    int* bpre   = (int*)ws;         ws += 64 * sizeof(int);
    int* sorted_src = (int*)ws;     ws += (size_t)E * sizeof(int);

    hipMemsetAsync(deg, 0, (size_t)N * sizeof(int), stream);

    int nb_n = (N + 255) / 256;
    int nb_e = (E + 255) / 256;
    int NB   = (N + CHUNK - 1) / CHUNK;   // 49 for N=100000 (<= 64)

    k_transform<<<nb_n, 256, 0, stream>>>(x, W, a_src, a_dst, hrow, al_d, dst, deg, N, E);
    k_scanA<<<NB, 256, 0, stream>>>(deg, bsum, N);
    k_scanB<<<1, 64, 0, stream>>>(bsum, bpre, rowptr, NB, N);
    k_scanC<<<NB, 256, 0, stream>>>(deg, bpre, rowptr, cursor, N);
    k_scatter<<<nb_e, 256, 0, stream>>>(src, dst, cursor, sorted_src, E);

    int nb_g = (N + WAVES_PER_BLOCK - 1) / WAVES_PER_BLOCK;
    k_gat<<<nb_g, 256, 0, stream>>>(rowptr, sorted_src, hrow, al_d, bias,
                                    (float*)d_out, N);
}

// Round 5
// 168.634 us; speedup vs baseline: 44.3032x; 1.7832x over previous
//
#include <hip/hip_runtime.h>
#include <math.h>

#define NHEADS 8
#define NC 9
#define NHC 72
#define FIN 12
#define WAVES_PER_BLOCK 4
#define ROWW 48         // words per node row: 36 (72 bf16) + 8 (al_s f32) + 4 pad = 192 B
#define ALS_OFF 36      // word offset of al_s within row
#define MAXBUK 512      // supports N <= 131072 (bucket = dst >> 8)
#define TILE 4096       // edges per k_bucketA block (256 thr x 16)

__device__ __forceinline__ float lrelu(float v) { return v > 0.f ? v : 0.2f * v; }

// round-to-nearest-even bf16 pack of two floats into one uint (a=low, b=high)
__device__ __forceinline__ unsigned pack_bf16(float a, float b) {
    unsigned ua = __float_as_uint(a); ua += 0x7fffu + ((ua >> 16) & 1u);
    unsigned ub = __float_as_uint(b); ub += 0x7fffu + ((ub >> 16) & 1u);
    return (ua >> 16) | (ub & 0xffff0000u);
}

// K1: per-node linear transform -> packed bf16 row [h | al_s]; al_d separate.
// Fused tail: bucket histogram of dst (LDS-aggregated, few global atomics).
__global__ void __launch_bounds__(256) k_transform(
    const float* __restrict__ x, const float* __restrict__ W,
    const float* __restrict__ a_src, const float* __restrict__ a_dst,
    unsigned* __restrict__ hrow, float* __restrict__ al_d,
    const int* __restrict__ dst, int* __restrict__ bucket_count,
    int N, int E, int nbuk)
{
    __shared__ float sW[FIN * NHC];
    __shared__ float sas[NHC];
    __shared__ float sad[NHC];
    __shared__ int bcnt[MAXBUK];
    int tid = threadIdx.x;
    for (int i = tid; i < FIN * NHC; i += blockDim.x) sW[i] = W[i];
    if (tid < NHC) { sas[tid] = a_src[tid]; sad[tid] = a_dst[tid]; }
    for (int i = tid; i < nbuk; i += blockDim.x) bcnt[i] = 0;
    __syncthreads();
    int n = blockIdx.x * blockDim.x + tid;
    if (n < N) {
        float xv[FIN];
        const float4* xp = reinterpret_cast<const float4*>(x + (size_t)n * FIN);
        float4 q0 = xp[0], q1 = xp[1], q2 = xp[2];
        xv[0] = q0.x; xv[1] = q0.y; xv[2] = q0.z; xv[3] = q0.w;
        xv[4] = q1.x; xv[5] = q1.y; xv[6] = q1.z; xv[7] = q1.w;
        xv[8] = q2.x; xv[9] = q2.y; xv[10] = q2.z; xv[11] = q2.w;

        float acc[NHC];
        #pragma unroll
        for (int j = 0; j < NHC; ++j) acc[j] = 0.f;
        #pragma unroll
        for (int k = 0; k < FIN; ++k) {
            float xk = xv[k];
            #pragma unroll
            for (int j = 0; j < NHC; ++j) acc[j] = fmaf(xk, sW[k * NHC + j], acc[j]);
        }

        unsigned* rp = hrow + (size_t)n * ROWW;
        #pragma unroll
        for (int l = 0; l < NHC / 2; ++l)
            rp[l] = pack_bf16(acc[2 * l], acc[2 * l + 1]);

        float* rf = reinterpret_cast<float*>(rp);
        #pragma unroll
        for (int hh = 0; hh < NHEADS; ++hh) {
            float ss = 0.f, dd = 0.f;
            #pragma unroll
            for (int c = 0; c < NC; ++c) {
                ss = fmaf(acc[hh * NC + c], sas[hh * NC + c], ss);
                dd = fmaf(acc[hh * NC + c], sad[hh * NC + c], dd);
            }
            rf[ALS_OFF + hh] = ss;
            al_d[(size_t)n * NHEADS + hh] = dd;
        }
    }
    // fused bucket histogram (LDS-aggregated)
    int stride = gridDim.x * blockDim.x;
    for (int i = blockIdx.x * blockDim.x + tid; i < E; i += stride)
        atomicAdd(&bcnt[dst[i] >> 8], 1);
    __syncthreads();
    for (int i = tid; i < nbuk; i += blockDim.x)
        if (bcnt[i]) atomicAdd(&bucket_count[i], bcnt[i]);
}

// K2: single-block scan of bucket counts -> bucket_base, gcur; rowptr[N]=E.
__global__ void __launch_bounds__(512) k_bscan(
    const int* __restrict__ bucket_count, int* __restrict__ bucket_base,
    int* __restrict__ gcur, int* __restrict__ rowptr, int nbuk, int N, int E)
{
    __shared__ int s[512];
    int t = threadIdx.x;
    int v = (t < nbuk) ? bucket_count[t] : 0;
    s[t] = v;
    __syncthreads();
    for (int off = 1; off < 512; off <<= 1) {
        int u = (t >= off) ? s[t - off] : 0;
        __syncthreads();
        s[t] += u;
        __syncthreads();
    }
    if (t < nbuk) {
        int ex = s[t] - v;
        bucket_base[t] = ex;
        gcur[t] = ex;
    }
    if (t == 0) { bucket_base[nbuk] = E; rowptr[N] = E; }
}

// K3: coarse scatter into buckets: packed (src | d_local<<24), 4B/edge.
__global__ void __launch_bounds__(256) k_bucketA(
    const int* __restrict__ src, const int* __restrict__ dst,
    int* __restrict__ gcur, unsigned* __restrict__ bpair, int E, int nbuk)
{
    __shared__ int cnt[MAXBUK];
    __shared__ int sbase[MAXBUK];
    int t = threadIdx.x;
    for (int i = t; i < nbuk; i += 256) cnt[i] = 0;
    __syncthreads();
    int base0 = blockIdx.x * TILE;
    int rk[16], bk[16];
    unsigned pk[16];
    #pragma unroll
    for (int j = 0; j < 16; ++j) {
        int i = base0 + j * 256 + t;          // coalesced
        if (i < E) {
            int d = dst[i];
            int sg = src[i];
            bk[j] = d >> 8;
            pk[j] = (unsigned)sg | ((unsigned)(d & 255) << 24);
            rk[j] = atomicAdd(&cnt[bk[j]], 1);
        } else bk[j] = -1;
    }
    __syncthreads();
    for (int b = t; b < nbuk; b += 256)
        if (cnt[b]) sbase[b] = atomicAdd(&gcur[b], cnt[b]);
    __syncthreads();
    #pragma unroll
    for (int j = 0; j < 16; ++j)
        if (bk[j] >= 0) bpair[sbase[bk[j]] + rk[j]] = pk[j];
}

// K4: one block per bucket: per-node counts -> rowptr, then fine scatter
// with LDS cursors (block exclusively owns its 256 nodes).
__global__ void __launch_bounds__(256) k_bucketB(
    const unsigned* __restrict__ bpair, const int* __restrict__ bucket_base,
    int* __restrict__ rowptr, int* __restrict__ sorted_src, int N)
{
    __shared__ int cnt[256];
    __shared__ int sc[256];
    int b = blockIdx.x;
    int t = threadIdx.x;
    int lo = bucket_base[b], hi = bucket_base[b + 1];
    cnt[t] = 0;
    __syncthreads();
    for (int i = lo + t; i < hi; i += 256)
        atomicAdd(&cnt[bpair[i] >> 24], 1);
    __syncthreads();
    int v = cnt[t];
    sc[t] = v;
    __syncthreads();
    for (int off = 1; off < 256; off <<= 1) {
        int u = (t >= off) ? sc[t - off] : 0;
        __syncthreads();
        sc[t] += u;
        __syncthreads();
    }
    int excl = sc[t] - v;
    int node = (b << 8) + t;
    if (node < N) rowptr[node] = lo + excl;
    __syncthreads();
    cnt[t] = lo + excl;                       // repurpose as absolute cursor
    __syncthreads();
    for (int i = lo + t; i < hi; i += 256) {
        unsigned w = bpair[i];
        int pos = atomicAdd(&cnt[w >> 24], 1);
        sorted_src[pos] = (int)(w & 0xFFFFFFu);
    }
}

// K5: one wave per dst node: no-max segment softmax + bf16 gather-aggregate + finalize.
__global__ void __launch_bounds__(256) k_gat(
    const int* __restrict__ rowptr, const int* __restrict__ sorted_src,
    const unsigned* __restrict__ hrow, const float* __restrict__ al_d,
    const float* __restrict__ bias, float* __restrict__ out, int N)
{
    __shared__ int   s_off[WAVES_PER_BLOCK][64];     // row BYTE offsets
    __shared__ float s_ex[WAVES_PER_BLOCK][64][9];   // [edge][head], pad 8->9
    __shared__ float s_den[WAVES_PER_BLOCK][8];
    __shared__ float s_out[WAVES_PER_BLOCK][NHC];
    __shared__ float s_v[WAVES_PER_BLOCK][NC];

    int wid  = threadIdx.x >> 6;
    int lane = threadIdx.x & 63;
    int n = blockIdx.x * WAVES_PER_BLOCK + wid;
    if (n >= N) return;                         // uniform per wave

    int base  = rowptr[n];
    int total = rowptr[n + 1] - base + 1;       // + implicit self-loop at index total-1

    int g  = lane >> 3;                         // edge-slot group (softmax phase)
    int hh = lane & 7;                          // head (softmax phase)
    float ald_h = al_d[(size_t)n * NHEADS + hh];

    bool act36 = lane < NHC / 2;
    int widx4 = act36 ? lane * 4 : 0;           // payload word byte-offset within row
    int c0 = 2 * lane, c1 = 2 * lane + 1;
    int ha = act36 ? c0 / NC : 0;
    int hb = act36 ? c1 / NC : 0;
    float accA = 0.f, accB = 0.f;
    float den_part = 0.f;

    const char* hbase = reinterpret_cast<const char*>(hrow);
    int als_boff = (ALS_OFF + hh) * 4;          // byte offset of my head's al_s in a row

    for (int cb = 0; cb < total; cb += 64) {
        int rem = total - cb;
        int clen = rem < 64 ? rem : 64;
        int clenR = (clen + 3) & ~3;            // guard-free round-up (<=64)

        // fill row byte-offsets for this chunk (j >= total-1 -> self row n; safe pad)
        int j = cb + lane;
        int s = n;
        if (j < total - 1) s = sorted_src[base + j];
        s_off[wid][lane] = s * (ROWW * 4);

        // softmax phase: lane (g,hh) handles local edges lj = k*8+g for head hh
        for (int k = 0; k * 8 < clenR; ++k) {
            int lj = k * 8 + g;
            int off = s_off[wid][lj];
            float als = *reinterpret_cast<const float*>(hbase + off + als_boff);
            float ex = 0.f;
            if (cb + lj < total) ex = __expf(lrelu(als + ald_h));
            s_ex[wid][lj][hh] = ex;
            den_part += ex;
        }

        // aggregation phase: guard-free, unrolled by 4
        for (int e = 0; e < clenR; e += 4) {
            #pragma unroll
            for (int p = 0; p < 4; ++p) {
                int ee = e + p;
                int off = s_off[wid][ee];
                unsigned w = *reinterpret_cast<const unsigned*>(hbase + off + widx4);
                float fa = __uint_as_float(w << 16);
                float fb = __uint_as_float(w & 0xffff0000u);
                accA = fmaf(s_ex[wid][ee][ha], fa, accA);
                accB = fmaf(s_ex[wid][ee][hb], fb, accB);
            }
        }
    }

    // denominator: 3-shuffle reduce across the 8 lanes sharing each head
    den_part += __shfl_xor(den_part, 8, 64);
    den_part += __shfl_xor(den_part, 16, 64);
    den_part += __shfl_xor(den_part, 32, 64);
    if (lane < 8) s_den[wid][lane] = den_part;

    if (act36) {
        float ia = 1.f / (s_den[wid][ha] + 1e-16f);
        float ib = 1.f / (s_den[wid][hb] + 1e-16f);
        s_out[wid][c0] = accA * ia;
        s_out[wid][c1] = accB * ib;
    }

    if (lane < NC) {
        float v = 0.f;
        #pragma unroll
        for (int h = 0; h < NHEADS; ++h) v += s_out[wid][h * NC + lane];
        v = v * (1.f / NHEADS) + bias[lane];
        s_v[wid][lane] = v;
        float mx = -INFINITY;
        #pragma unroll
        for (int c = 0; c < NC; ++c) mx = fmaxf(mx, s_v[wid][c]);
        float sum = 0.f;
        #pragma unroll
        for (int c = 0; c < NC; ++c) sum += __expf(s_v[wid][c] - mx);
        float lse = mx + __logf(sum);
        out[(size_t)n * NC + lane] = s_v[wid][lane] - lse;
    }
}

extern "C" void kernel_launch(void* const* d_in, const int* in_sizes, int n_in,
                              void* d_out, int out_size, void* d_ws, size_t ws_size,
                              hipStream_t stream)
{
    const float* x     = (const float*)d_in[0];
    const int*   ei    = (const int*)d_in[1];
    const float* W     = (const float*)d_in[2];
    const float* a_src = (const float*)d_in[3];
    const float* a_dst = (const float*)d_in[4];
    const float* bias  = (const float*)d_in[5];

    int N = in_sizes[0] / FIN;   // 100000
    int E = in_sizes[1] / 2;     // 1600000
    const int* src = ei;
    const int* dst = ei + E;
    int nbuk = (N + 255) >> 8;   // 391

    char* ws = (char*)d_ws;
    unsigned* hrow = (unsigned*)ws;     ws += (size_t)N * ROWW * sizeof(unsigned);
    float* al_d = (float*)ws;           ws += (size_t)N * NHEADS * sizeof(float);
    int* rowptr = (int*)ws;             ws += (size_t)(N + 1) * sizeof(int);
    int* bucket_count = (int*)ws;       ws += (size_t)(MAXBUK + 1) * sizeof(int);
    int* bucket_base  = (int*)ws;       ws += (size_t)(MAXBUK + 1) * sizeof(int);
    int* gcur = (int*)ws;               ws += (size_t)MAXBUK * sizeof(int);
    unsigned* bpair = (unsigned*)ws;    ws += (size_t)E * sizeof(unsigned);
    int* sorted_src = (int*)ws;         ws += (size_t)E * sizeof(int);

    hipMemsetAsync(bucket_count, 0, (size_t)(MAXBUK + 1) * sizeof(int), stream);

    int nb_n = (N + 255) / 256;
    int nb_a = (E + TILE - 1) / TILE;

    k_transform<<<nb_n, 256, 0, stream>>>(x, W, a_src, a_dst, hrow, al_d,
                                          dst, bucket_count, N, E, nbuk);
    k_bscan<<<1, 512, 0, stream>>>(bucket_count, bucket_base, gcur, rowptr,
                                   nbuk, N, E);
    k_bucketA<<<nb_a, 256, 0, stream>>>(src, dst, gcur, bpair, E, nbuk);
    k_bucketB<<<nbuk, 256, 0, stream>>>(bpair, bucket_base, rowptr, sorted_src, N);

    int nb_g = (N + WAVES_PER_BLOCK - 1) / WAVES_PER_BLOCK;
    k_gat<<<nb_g, 256, 0, stream>>>(rowptr, sorted_src, hrow, al_d, bias,
                                    (float*)d_out, N);
}